// Round 9
// baseline (7081.108 us; speedup 1.0000x reference)
//
#include <hip/hip_runtime.h>
#include <math.h>

#define NPTS 3072
#define BLK  256
#define NCLS 10
#define NKB  48     // wave64 vis batches: 3072/64

#pragma clang fp contract(off)

// 64-lane min-reduce via DPP butterfly; result valid in lane 63 (R6/R7/R8-proven).
__device__ __forceinline__ unsigned dppmin_u32(unsigned x) {
    unsigned t;
    t = (unsigned)__builtin_amdgcn_update_dpp(-1, (int)x, 0x111, 0xF, 0xF, false); x = x < t ? x : t; // row_shr:1
    t = (unsigned)__builtin_amdgcn_update_dpp(-1, (int)x, 0x112, 0xF, 0xF, false); x = x < t ? x : t; // row_shr:2
    t = (unsigned)__builtin_amdgcn_update_dpp(-1, (int)x, 0x114, 0xF, 0xF, false); x = x < t ? x : t; // row_shr:4
    t = (unsigned)__builtin_amdgcn_update_dpp(-1, (int)x, 0x118, 0xF, 0xF, false); x = x < t ? x : t; // row_shr:8
    t = (unsigned)__builtin_amdgcn_update_dpp(-1, (int)x, 0x142, 0xF, 0xF, false); x = x < t ? x : t; // row_bcast:15
    t = (unsigned)__builtin_amdgcn_update_dpp(-1, (int)x, 0x143, 0xF, 0xF, false); x = x < t ? x : t; // row_bcast:31
    return x;
}

__device__ __forceinline__ float readlanef(float v, int l) {
    return __int_as_float(__builtin_amdgcn_readlane(__float_as_int(v), l));
}

__global__ __launch_bounds__(BLK)
void frustum_cluster(const float* __restrict__ pts,
                     const int* __restrict__ lblg,
                     const float* __restrict__ anch,
                     int* __restrict__ out,
                     int* __restrict__ ws)
{
    const int tid  = threadIdx.x;
    const int lane = tid & 63;
    const int wid  = tid >> 6;

    // ---------------- global workspace ----------------
    int*    dlg    = ws + 16;                          // 3072 ints
    int*    remapg = ws + 4096;                        // 3072 ints
    float4* gstats = (float4*)(ws + 8192);             // per-cluster stats (epilogue)

    // ---------------- LDS (~60.4 KB) ----------------
    __shared__ float4 gpts[NPTS];                      // class-grouped points; epilogue: ordered clusters
    __shared__ unsigned short vor16[NPTS];             // visit order (pos); epilogue: counts cache
    __shared__ unsigned short startv[NPTS];            // run start per label
    __shared__ float amdxy[NCLS], amdz[NCLS], r2a[NCLS];
    __shared__ int cntL[NCLS], curL[NCLS], baseL[NCLS];
    __shared__ int p0s, nclusS;

    if (tid < NCLS) {
        float l = anch[tid*3+0], w = anch[tid*3+1], h = anch[tid*3+2];
        amdxy[tid] = fmaxf(l, w);
        amdz[tid]  = h;
        r2a[tid]   = sqrtf((l*l + w*w) + h*h) * 0.5f;  // norm(anchor)/2, ref op order
        cntL[tid] = 0; curL[tid] = 0;
    }
    __syncthreads();
    for (int j = tid; j < NPTS; j += BLK) atomicAdd(&cntL[lblg[j]], 1);
    __syncthreads();
    if (tid == 0) { int acc = 0; for (int c = 0; c < NCLS; ++c) { baseL[c] = acc; acc += cntL[c]; } }
    __syncthreads();
    // scatter into class-grouped layout; within-class order irrelevant (tie-break via orig idx)
    for (int j = tid; j < NPTS; j += BLK) {
        int c = lblg[j];
        int pos = baseL[c] + atomicAdd(&curL[c], 1);
        float4 e;
        e.x = pts[3*j]; e.y = pts[3*j+1]; e.z = pts[3*j+2];
        e.w = __uint_as_float(((unsigned)j << 4) | (unsigned)c);
        gpts[pos] = e;
        if (j == 0) p0s = pos;
    }
    if (tid == 0) startv[0] = 0;
    __syncthreads();   // scatter + p0s visible; waves 1-3 fall through to the join barrier below

    // ================= single-wave scan: wave 0, ZERO barriers =================
    if (wid == 0) {
        // packed per-class base/count (12-bit fields, classes 0-4 / 5-9), in registers
        unsigned long long baseA = 0, baseB = 0, cnt0A = 0, cnt0B = 0;
        for (int c = 0; c < 5; ++c) {
            baseA |= (unsigned long long)baseL[c]   << (12*c);
            cnt0A |= (unsigned long long)cntL[c]    << (12*c);
            baseB |= (unsigned long long)baseL[c+5] << (12*c);
            cnt0B |= (unsigned long long)cntL[c+5]  << (12*c);
        }
        unsigned long long cntA = cnt0A, cntB = cnt0B; // live (unvisited) counts
        // class constants parked in lanes 0-9, fetched by wave-uniform readlane (no LDS)
        float axyL = 0.f, azL = 0.f, r2L = 0.f;
        if (lane < NCLS) { axyL = amdxy[lane]; azL = amdz[lane]; r2L = r2a[lane]; }

        const int p0 = p0s;
        if (lane == 0) vor16[0] = (unsigned short)p0;
        int cls = lblg[0];
        { int sh = (cls < 5 ? cls : cls - 5) * 12;     // point 0 starts visited
          if (cls < 5) cntA -= 1ull << sh; else cntB -= 1ull << sh; }
        unsigned long long vis = 0;                    // bit k -> position p = lane + 64k
        if (lane == (p0 & 63)) vis |= 1ull << (p0 >> 6);

        float pcx = pts[0], pcy = pts[1], pcz = pts[2];
        float sx = pcx, sy = pcy, sz = pcz, scnt = 1.0f;
        float icx = pcx, icy = pcy, icz = pcz;
        int   lab = 0;
        float amdxy_c = readlanef(axyL, cls), amdz_c = readlanef(azL, cls), r2_c = readlanef(r2L, cls);

        for (int t = 0; t < NPTS-1; ++t) {
            const int c  = cls;
            const int sh = (c < 5 ? c : c - 5) * 12;
            const int live = (int)(((c < 5 ? cntA : cntB) >> sh) & 0xFFFull);
            unsigned bestk = 0xFFFFFFFFu, bestm = 0xFFFFFFFFu;
            float bx = 0.f, by = 0.f, bz = 0.f;
            if (live > 0) {
                // winner = nearest unvisited same-class point (pen-0 dominance, R5 lex proof)
                const int base = (int)(((c < 5 ? baseA : baseB) >> sh) & 0xFFFull);
                const int cnt0 = (int)(((c < 5 ? cnt0A : cnt0B) >> sh) & 0xFFFull);
                const int kbeg = base >> 6;
                const int kend = (base + cnt0 - 1) >> 6;
                // 8 predicated batches cover cnt0 <= 8*64-63 = 449 >> max class count (~360 at 3 sigma)
                #pragma unroll
                for (int kk = 0; kk < 8; ++kk) {
                    const int k = kbeg + kk;
                    const bool kok = (k <= kend);
                    const int p = lane + (k << 6);
                    float4 e = gpts[kok ? p : lane];   // clamped: always in-bounds, conflict-free
                    unsigned pk = __float_as_uint(e.w);
                    float dx = pcx - e.x, dy = pcy - e.y, dz = pcz - e.z;
                    float s = (dx*dx + dy*dy) + dz*dz; // ref order, contract off
                    unsigned key  = __float_as_uint(s);
                    unsigned meta = ((pk >> 4) << 16) | ((pk & 15u) << 12) | (unsigned)p;
                    bool ok = kok && (p >= base) && (p < base + cnt0) && !((vis >> k) & 1ull);
                    if (ok && (key < bestk || (key == bestk && meta < bestm))) {
                        bestk = key; bestm = meta; bx = e.x; by = e.y; bz = e.z;
                    }
                }
            } else {                                   // class exhausted (rare): full fallback sweep
                for (int k = 0; k < NKB; ++k) {
                    const int p = lane + (k << 6);
                    float4 e = gpts[p];
                    unsigned pk = __float_as_uint(e.w);
                    float dx = pcx - e.x, dy = pcy - e.y, dz = pcz - e.z;
                    float s = (dx*dx + dy*dy) + dz*dz;
                    unsigned key  = __float_as_uint(s)
                                  | (((pk & 15u) != (unsigned)c) ? 0x80000000u : 0u);
                    unsigned meta = ((pk >> 4) << 16) | ((pk & 15u) << 12) | (unsigned)p;
                    bool ok = !((vis >> k) & 1ull);
                    if (ok && (key < bestk || (key == bestk && meta < bestm))) {
                        bestk = key; bestm = meta; bx = e.x; by = e.y; bz = e.z;
                    }
                }
            }
            // in-wave argmin: DPP reduce on key; meta (min orig idx) resolves exact-s ties
            unsigned wk = (unsigned)__builtin_amdgcn_readlane((int)dppmin_u32(bestk), 63);
            bool cand = (bestk == wk);
            unsigned long long msk = __ballot(cand);
            if (__popcll(msk) > 1) {
                unsigned wm = (unsigned)__builtin_amdgcn_readlane(
                    (int)dppmin_u32(cand ? bestm : 0xFFFFFFFFu), 63);
                msk = __ballot(cand && bestm == wm);
            }
            int wl = __ffsll((unsigned long long)msk) - 1;
            unsigned m = (unsigned)__builtin_amdgcn_readlane((int)bestm, wl);
            float pix = readlanef(bx, wl), piy = readlanef(by, wl), piz = readlanef(bz, wl);
            int pos  = (int)(m & 0xFFFu);
            int clsE = (int)((m >> 12) & 0xFu);

            float dx = pcx - pix, dy = pcy - piy, dz = pcz - piz;
            // angle clause structurally always-false: omitted (R1-proven)
            bool nc = (fabsf(dx) > amdxy_c) || (fabsf(dy) > amdxy_c) || (fabsf(dz) > amdz_c);
            nc = nc || (clsE != c);
            float dn = sqrtf((dx*dx + dy*dy) + dz*dz);
            nc = nc || (dn > r2_c);
            float ex = icx - pix, ey = icy - piy, ez = icz - piz;
            float en = sqrtf((ex*ex + ey*ey) + ez*ez);
            nc = nc || (en > r2_c);
            if (nc) {
                lab += 1;
                if (lane == 0) startv[lab] = (unsigned short)(t + 1);
                sx = pix; sy = piy; sz = piz; scnt = 1.0f;
            } else {
                sx = sx + pix; sy = sy + piy; sz = sz + piz; scnt = scnt + 1.0f;
            }
            icx = sx / scnt; icy = sy / scnt; icz = sz / scnt;
            if (lane == 0) vor16[t+1] = (unsigned short)pos;
            if (lane == (pos & 63)) vis |= 1ull << (pos >> 6);   // immediate in-register removal
            { int shE = (clsE < 5 ? clsE : clsE - 5) * 12;
              if (clsE < 5) cntA -= 1ull << shE; else cntB -= 1ull << shE; }
            cls = clsE;
            pcx = pix; pcy = piy; pcz = piz;
            amdxy_c = readlanef(axyL, cls); amdz_c = readlanef(azL, cls); r2_c = readlanef(r2L, cls);
        }
        if (lane == 0) nclusS = lab;
    }
    __syncthreads();   // join: waves 1-3 were parked here during the scan
    const int nclus = nclusS;                          // num_clusters (exclusive)

    // ---------------- epilogue (R8-proven, 256 threads) ----------------
    // (a) runs in visit order -> per-cluster stats (bitwise == scan's incremental sums) + dl to global
    for (int c2 = tid; c2 <= nclus; c2 += BLK) {
        int s0 = startv[c2];
        int s1 = (c2 < nclus) ? (int)startv[c2+1] : NPTS;
        float ax = 0.f, ay = 0.f, az = 0.f;
        int clsF = 0;
        for (int s = s0; s < s1; ++s) {
            float4 e = gpts[vor16[s]];
            unsigned pk = __float_as_uint(e.w);
            if (s == s0) clsF = (int)(pk & 15u);
            ax = ax + e.x; ay = ay + e.y; az = az + e.z;
            dlg[pk >> 4] = c2;
        }
        if (c2 < nclus) {
            float fc = (float)(s1 - s0);
            float4 g;
            g.x = ax / fc; g.y = ay / fc; g.z = az / fc;
            g.w = __uint_as_float(((unsigned)(s1 - s0) << 4) | (unsigned)clsF);
            gstats[c2] = g;
        }
    }
    for (int c2 = tid; c2 < NPTS; c2 += BLK) remapg[c2] = c2;
    __syncthreads();

    // (b) counts cache + stable rank sort (counts desc, index asc) -> ordered clusters
    unsigned short* cnt16 = vor16;                     // vor16 dead after (a)
    for (int c2 = tid; c2 < nclus; c2 += BLK)
        cnt16[c2] = (unsigned short)(__float_as_uint(gstats[c2].w) >> 4);
    __syncthreads();
    float4* slab = gpts;                               // gpts dead after (a)
    for (int c2 = tid; c2 < nclus; c2 += BLK) {
        int cnt = (int)cnt16[c2];
        int r = 0;
        for (int j = 0; j < nclus; ++j) {
            int c3 = (int)cnt16[j];
            r += (int)((c3 > cnt) || (c3 == cnt && j < c2));
        }
        float4 g = gstats[c2];
        float4 oe;
        oe.x = g.x; oe.y = g.y; oe.z = g.z;
        oe.w = __uint_as_float(((unsigned)c2 << 5) | ((__float_as_uint(g.w) & 15u) << 1) | 1u);
        slab[r] = oe;
    }
    __syncthreads();

    // (c) sequential merge (proven): absorbers never later absorbed -> 1-level remap
    for (int i = 0; i < nclus; ++i) {
        float4 ei = slab[i];
        unsigned wi = __float_as_uint(ei.w);
        if (wi & 1u) {
            int   clsI = (int)((wi >> 1) & 15u);
            int   orgI = (int)(wi >> 5);
            float r2   = r2a[clsI];
            for (int j = i + 1 + tid; j < nclus; j += BLK) {
                float4 ej = slab[j];
                unsigned wj = __float_as_uint(ej.w);
                if ((wj & 1u) && ((int)((wj >> 1) & 15u) == clsI)) {
                    float ddx = ej.x - ei.x, ddy = ej.y - ei.y, ddz = ej.z - ei.z;
                    float dd = sqrtf((ddx*ddx + ddy*ddy) + ddz*ddz);
                    if (dd < r2) {
                        ej.w = __uint_as_float(wj & ~1u);
                        slab[j] = ej;
                        remapg[wj >> 5] = orgI;
                    }
                }
            }
        }
        __syncthreads();
    }

    // (d) final relabel
    for (int p = tid; p < NPTS; p += BLK) out[p] = remapg[dlg[p]];
}

extern "C" void kernel_launch(void* const* d_in, const int* in_sizes, int n_in,
                              void* d_out, int out_size, void* d_ws, size_t ws_size,
                              hipStream_t stream) {
    const float* pts  = (const float*)d_in[0];   // [3072,3] f32
    const int*   lbl  = (const int*)d_in[1];     // [3072] i32
    const float* anch = (const float*)d_in[2];   // [10,3] f32
    frustum_cluster<<<dim3(1), dim3(BLK), 0, stream>>>(pts, lbl, anch,
                                                       (int*)d_out, (int*)d_ws);
}